// Round 1
// 274.834 us; speedup vs baseline: 1.1591x; 1.1591x over previous
//
#include <hip/hip_runtime.h>
#include <hip/hip_bf16.h>

#define B_ 256
#define L_ 100
#define F_ 8
#define P_ 4
#define E_ 64
#define H_ 4
#define D_ 64
#define C_ 32
#define V_ 10000
#define TOWER_IN_ 1312
#define LN_EPS 0.001f
#define LCH_ 4    // l's per attention block
#define NCH_ 25   // number of l-chunks
#define ZK_ 40    // padded k-stride for sZt (80B: 16B-aligned, conflict-free)

typedef __attribute__((ext_vector_type(8))) short bf8v;           // 8 bf16 (4 VGPRs)
typedef __attribute__((ext_vector_type(8))) unsigned short us8;   // 8 u16
typedef __attribute__((ext_vector_type(4))) float f4v;            // 4 f32 acc

__device__ __forceinline__ unsigned short f2bf(float x) {
    __hip_bfloat16 h = __float2bfloat16(x);
    return __builtin_bit_cast(unsigned short, h);
}

// raw barrier: LDS-drain + s_barrier, NO vmcnt drain (prefetch loads stay in flight)
#define BARRIER() do { \
    asm volatile("s_waitcnt lgkmcnt(0)" ::: "memory"); \
    __builtin_amdgcn_s_barrier(); \
    asm volatile("" ::: "memory"); \
} while (0)

// ---------------------------------------------------------------------------
// Kernel P: precompute MT[l,h][o][e] = (Qh Kh^T)^T and WT[l,h][o][e] = (Vh Lh)^T
// in bf16.  grid = 400 blocks, 256 threads.   (verified R3/R4)
// ---------------------------------------------------------------------------
__global__ __launch_bounds__(256) void precomp_kernel(
    const float* __restrict__ q_w, const float* __restrict__ k_w,
    const float* __restrict__ v_w, const float* __restrict__ lin_w,
    unsigned short* __restrict__ wsMT, unsigned short* __restrict__ wsWT)
{
    __shared__ float sA[64][65];
    __shared__ float sB[64][65];
    const int t = threadIdx.x;
    const int l = blockIdx.x >> 2;
    const int h = blockIdx.x & 3;
    const size_t obase = (size_t)(l * 4 + h) * 4096;

    for (int i = 0; i < 16; ++i) {
        int idx = t + i * 256;
        int e = idx >> 6, d = idx & 63;
        sA[e][d] = q_w[(l * 64 + e) * 256 + h * 64 + d];
        sB[e][d] = k_w[(l * 64 + e) * 256 + h * 64 + d];
    }
    __syncthreads();
    for (int i = 0; i < 16; ++i) {
        int idx = t + i * 256;
        int o = idx >> 6, e = idx & 63;
        float s = 0.f;
        #pragma unroll 8
        for (int d = 0; d < 64; ++d) s += sA[e][d] * sB[o][d];
        wsMT[obase + idx] = f2bf(s);
    }
    __syncthreads();

    for (int i = 0; i < 16; ++i) {
        int idx = t + i * 256;
        int dd = idx >> 6, oo = idx & 63;
        sB[dd][oo] = lin_w[l * 16384 + (h * 64 + dd) * 64 + oo];
    }
    for (int i = 0; i < 16; ++i) {
        int idx = t + i * 256;
        int e = idx >> 6, d = idx & 63;
        sA[e][d] = v_w[(l * 64 + e) * 256 + h * 64 + d];
    }
    __syncthreads();
    for (int i = 0; i < 16; ++i) {
        int idx = t + i * 256;
        int o = idx >> 6, e = idx & 63;
        float s = 0.f;
        #pragma unroll 8
        for (int d = 0; d < 64; ++d) s += sA[e][d] * sB[d][o];
        wsWT[obase + idx] = f2bf(s);
    }
}

// ---------------------------------------------------------------------------
// Kernel W: transpose tower weights to bf16 [n][k].  grid = 1952, 256 thr.
// ---------------------------------------------------------------------------
__global__ __launch_bounds__(256) void prep_kernel(
    const float* __restrict__ w1, const float* __restrict__ w2,
    const float* __restrict__ w3,
    unsigned short* __restrict__ Wt1, unsigned short* __restrict__ Wt2,
    unsigned short* __restrict__ Wt3)
{
    __shared__ float tile[32][33];
    int bx = blockIdx.x;
    const float* src; unsigned short* dst; int K, N, tk, tn;
    if (bx < 1312)      { src = w1; dst = Wt1; K = 1312; N = 1024; tk = bx / 32;  tn = bx % 32; }
    else if (bx < 1824) { int i = bx - 1312; src = w2; dst = Wt2; K = 1024; N = 512; tk = i / 16; tn = i % 16; }
    else                { int i = bx - 1824; src = w3; dst = Wt3; K = 512;  N = 256; tk = i / 8;  tn = i % 8; }
    const int k0 = tk * 32, n0 = tn * 32;
    const int rr = threadIdx.x >> 5, cc = threadIdx.x & 31;
    #pragma unroll
    for (int i = 0; i < 4; ++i) {
        int r = rr * 4 + i;
        tile[r][cc] = src[(size_t)(k0 + r) * N + n0 + cc];
    }
    __syncthreads();
    #pragma unroll
    for (int i = 0; i < 4; ++i) {
        int r = rr * 4 + i;
        dst[(size_t)(n0 + r) * K + k0 + cc] = f2bf(tile[cc][r]);
    }
}

// ---------------------------------------------------------------------------
// Kernel A: fused attention.  grid = NCH_*32 blocks, 256 threads = 4 waves.
// This revision: raw barriers (no vmcnt drain) + gather/bfrag prefetch +
// conflict-free gather writes + sZt stride pad + 5 barriers/l (was 7).
// ---------------------------------------------------------------------------
__global__ __launch_bounds__(256, 3) void attn_kernel(
    const int* __restrict__ ubs_feature, const float* __restrict__ item_tables,
    const unsigned short* __restrict__ wsMT, const unsigned short* __restrict__ wsWT,
    const float* __restrict__ lin_b, const float* __restrict__ ln_g,
    const float* __restrict__ ln_b, float* __restrict__ ubs_acc)
{
    __shared__ __align__(16) unsigned short sUE[64][72];       // rows=b_loc*8+f
    __shared__ __align__(16) unsigned short sT[64][136];       // cols=hl*64+e'
    __shared__ __align__(16) unsigned short sZt[4][64][ZK_];   // [pair][e][k] (k<32 used)
    __shared__ __align__(16) unsigned short sAblk[4][16][32];  // [pair][r][k]
    __shared__ float sLng[64], sLnb[64], sLinb[LCH_][64];

    const int t = threadIdx.x;
    const int c = blockIdx.x >> 5;            // l-chunk 0..24
    const int b0 = (blockIdx.x & 31) * 8;
    const int wv = t >> 6, lane = t & 63, quad = lane >> 4, cl = lane & 15;
    const int role = wv >> 1, hlw = wv & 1;

    // gather mapping: wave wv owns rows [16wv,16wv+16); 4 lanes/row, 16 floats/lane
    const int grow = wv * 16 + (lane >> 2);   // row in [0,64) = b_loc*8 + f
    const int gseg = lane & 3;                // 16-float (32B-pair) segment
    const int gb = b0 + (grow >> 3), gf = grow & 7;

    if (t < 64) { sLng[t] = ln_g[t]; sLnb[t] = ln_b[t]; }
    if (t >= 64 && t < 128) {
        #pragma unroll
        for (int li = 0; li < LCH_; ++li)
            sLinb[li][t - 64] = lin_b[(c * LCH_ + li) * 64 + (t - 64)];
    }

    // all 4 v-indices up front (kills the idx->row dependent-load chain)
    int vidx[LCH_];
    #pragma unroll
    for (int li = 0; li < LCH_; ++li)
        vidx[li] = ubs_feature[(gb * L_ + c * LCH_ + li) * F_ + gf];

    float4 pf[4];
    bf8v bfrag[4][2];

    auto load_bfrag = [&](int lh) {   // lh = l*4 + half*2 + hlw
        const unsigned short* Bsrc = (role == 0 ? wsMT : wsWT) + ((size_t)lh * 4096);
        #pragma unroll
        for (int nt = 0; nt < 4; ++nt)
            #pragma unroll
            for (int k2 = 0; k2 < 2; ++k2)
                bfrag[nt][k2] = *(const bf8v*)(Bsrc + (nt * 16 + cl) * 64 + k2 * 32 + quad * 8);
    };
    auto load_pf = [&](int li) {
        const float* srcp = item_tables + ((size_t)gf * V_ + vidx[li]) * 64 + gseg * 16;
        #pragma unroll
        for (int j = 0; j < 4; ++j) pf[j] = ((const float4*)srcp)[j];
    };
    auto store_ue = [&]() {
        us8 u0, u1;
        u0[0] = f2bf(pf[0].x); u0[1] = f2bf(pf[0].y); u0[2] = f2bf(pf[0].z); u0[3] = f2bf(pf[0].w);
        u0[4] = f2bf(pf[1].x); u0[5] = f2bf(pf[1].y); u0[6] = f2bf(pf[1].z); u0[7] = f2bf(pf[1].w);
        u1[0] = f2bf(pf[2].x); u1[1] = f2bf(pf[2].y); u1[2] = f2bf(pf[2].z); u1[3] = f2bf(pf[2].w);
        u1[4] = f2bf(pf[3].x); u1[5] = f2bf(pf[3].y); u1[6] = f2bf(pf[3].z); u1[7] = f2bf(pf[3].w);
        *(us8*)&sUE[grow][gseg * 16]     = u0;   // 8-lane groups span all 32 banks
        *(us8*)&sUE[grow][gseg * 16 + 8] = u1;
    };

    // l0 gather + first bfrag prefetch
    load_pf(0);
    load_bfrag((c * LCH_) * 4 + hlw);
    store_ue();
    BARRIER();

    float lnacc[16];
    #pragma unroll
    for (int i = 0; i < 16; ++i) lnacc[i] = 0.f;

    for (int li = 0; li < LCH_; ++li) {
        const int l = c * LCH_ + li;

        // issue next-l gather loads now; they ride across all barriers (no vmcnt drain)
        if (li + 1 < LCH_) load_pf(li + 1);

        f4v accO[4];
        #pragma unroll
        for (int nt = 0; nt < 4; ++nt) accO[nt] = {0.f, 0.f, 0.f, 0.f};

        #pragma unroll
        for (int half = 0; half < 2; ++half) {
            // ---- phase A: waves 0,1 -> T (h=half*2+hlw); waves 2,3 -> Zt ----
            #pragma unroll
            for (int m = 0; m < 4; ++m) {
                bf8v a0 = *(const bf8v*)&sUE[m * 16 + cl][quad * 8];
                bf8v a1 = *(const bf8v*)&sUE[m * 16 + cl][32 + quad * 8];
                #pragma unroll
                for (int nt = 0; nt < 4; ++nt) {
                    f4v acc = {0.f, 0.f, 0.f, 0.f};
                    acc = __builtin_amdgcn_mfma_f32_16x16x32_bf16(a0, bfrag[nt][0], acc, 0, 0, 0);
                    acc = __builtin_amdgcn_mfma_f32_16x16x32_bf16(a1, bfrag[nt][1], acc, 0, 0, 0);
                    if (role == 0) {
                        #pragma unroll
                        for (int j = 0; j < 4; ++j)
                            sT[m * 16 + quad * 4 + j][hlw * 64 + nt * 16 + cl] = f2bf(acc[j]);
                    } else {
                        ushort4 zp;
                        zp.x = f2bf(acc[0]); zp.y = f2bf(acc[1]);
                        zp.z = f2bf(acc[2]); zp.w = f2bf(acc[3]);
                        const int k0 = (quad >> 1) * 16 + hlw * 8 + (quad & 1) * 4;
                        *(ushort4*)&sZt[m][nt * 16 + cl][k0] = zp;
                    }
                }
            }
            // prefetch the next half's / next l's B fragments (hidden under scores+PV)
            if (half == 0)            load_bfrag(l * 4 + 2 + hlw);
            else if (li + 1 < LCH_)   load_bfrag((l + 1) * 4 + hlw);
            BARRIER();

            // ---- scores + softmax + Ablk (wave = pair) ----
            {
                const int p = wv;
                const bool valid = (cl >> 3) == (quad >> 1);
                #pragma unroll
                for (int hl = 0; hl < 2; ++hl) {
                    bf8v a0s = *(const bf8v*)&sT[p * 16 + cl][hl * 64 + quad * 8];
                    bf8v a1s = *(const bf8v*)&sT[p * 16 + cl][hl * 64 + 32 + quad * 8];
                    bf8v u0 = *(const bf8v*)&sUE[p * 16 + cl][quad * 8];
                    bf8v u1 = *(const bf8v*)&sUE[p * 16 + cl][32 + quad * 8];
                    f4v acc = {0.f, 0.f, 0.f, 0.f};
                    acc = __builtin_amdgcn_mfma_f32_16x16x32_bf16(a0s, u0, acc, 0, 0, 0);
                    acc = __builtin_amdgcn_mfma_f32_16x16x32_bf16(a1s, u1, acc, 0, 0, 0);
                    const int kk = hl * 8 + (cl & 7) + (cl >> 3) * 16;
                    #pragma unroll
                    for (int j = 0; j < 4; ++j) {
                        float v = acc[j] * 0.125f;
                        float mx = v;
                        mx = fmaxf(mx, __shfl_xor(mx, 1));
                        mx = fmaxf(mx, __shfl_xor(mx, 2));
                        mx = fmaxf(mx, __shfl_xor(mx, 4));
                        float ex = __expf(v - mx);
                        float sm = ex;
                        sm += __shfl_xor(sm, 1);
                        sm += __shfl_xor(sm, 2);
                        sm += __shfl_xor(sm, 4);
                        float aw = valid ? ex * __builtin_amdgcn_rcpf(sm) : 0.f;
                        sAblk[p][quad * 4 + j][kk] = f2bf(aw);
                    }
                }
            }

            // ---- PV (same-wave sAblk dependency: no barrier needed) ----
            {
                const int p = wv;
                bf8v a0p = *(const bf8v*)&sAblk[p][cl][quad * 8];
                #pragma unroll
                for (int nt = 0; nt < 4; ++nt) {
                    bf8v bz = *(const bf8v*)&sZt[p][nt * 16 + cl][quad * 8];
                    accO[nt] = __builtin_amdgcn_mfma_f32_16x16x32_bf16(a0p, bz, accO[nt], 0, 0, 0);
                }
            }
            BARRIER();
        }

        // ---- +lin_b, LayerNorm per row over 64 cols, accumulate over l ----
        {
            float x[16];
            #pragma unroll
            for (int nt = 0; nt < 4; ++nt)
                #pragma unroll
                for (int j = 0; j < 4; ++j)
                    x[nt * 4 + j] = accO[nt][j] + sLinb[li][nt * 16 + cl];
            #pragma unroll
            for (int j = 0; j < 4; ++j) {
                float s = x[j] + x[4 + j] + x[8 + j] + x[12 + j];
                #pragma unroll
                for (int m = 1; m < 16; m <<= 1) s += __shfl_xor(s, m);
                float mean = s * (1.f / 64.f);
                float q = 0.f;
                #pragma unroll
                for (int nt = 0; nt < 4; ++nt) { float d = x[nt * 4 + j] - mean; q += d * d; }
                #pragma unroll
                for (int m = 1; m < 16; m <<= 1) q += __shfl_xor(q, m);
                float rst = rsqrtf(q * (1.f / 64.f) + LN_EPS);
                #pragma unroll
                for (int nt = 0; nt < 4; ++nt) {
                    int col = nt * 16 + cl;
                    lnacc[nt * 4 + j] += (x[nt * 4 + j] - mean) * rst * sLng[col] + sLnb[col];
                }
            }
        }

        // write next-l UE rows (prefetched); all waves are past scores(h1) reads
        if (li + 1 < LCH_) {
            store_ue();
            BARRIER();
        }
    }

    // ---- accumulate into ubs_acc ----
    #pragma unroll
    for (int j = 0; j < 4; ++j) {
        const int row = wv * 16 + quad * 4 + j;
        const int b = b0 + (row >> 3), f = row & 7;
        #pragma unroll
        for (int nt = 0; nt < 4; ++nt)
            atomicAdd(&ubs_acc[(size_t)b * 512 + f * 64 + nt * 16 + cl], lnacc[nt * 4 + j]);
    }
}

// ---------------------------------------------------------------------------
// block-wide sum over 256 threads (4 waves)
// ---------------------------------------------------------------------------
__device__ __forceinline__ float block_reduce_sum(float v, float* sRed) {
    #pragma unroll
    for (int m = 1; m < 64; m <<= 1) v += __shfl_xor(v, m, 64);
    int wave = threadIdx.x >> 6, lane = threadIdx.x & 63;
    __syncthreads();
    if (lane == 0) sRed[wave] = v;
    __syncthreads();
    return sRed[0] + sRed[1] + sRed[2] + sRed[3];
}

// ---------------------------------------------------------------------------
// Kernel R: ubs = relu(acc/L) and gather concat -> X bf16 [256][1312]
// ---------------------------------------------------------------------------
__global__ __launch_bounds__(256) void reduceX_kernel(
    const float* __restrict__ ubs_acc,
    const int* __restrict__ target_ad, const int* __restrict__ profile_feature,
    const float* __restrict__ context,
    const float* __restrict__ item_tables, const float* __restrict__ profile_tables,
    unsigned short* __restrict__ X)
{
    const int b = blockIdx.x, t = threadIdx.x;
    const float2 v = *(const float2*)(ubs_acc + (size_t)b * 512 + t * 2);
    X[b * TOWER_IN_ + t * 2]     = f2bf(fmaxf(v.x * 0.01f, 0.f));
    X[b * TOWER_IN_ + t * 2 + 1] = f2bf(fmaxf(v.y * 0.01f, 0.f));
    for (int cc = 512 + t; cc < TOWER_IN_; cc += 256) {
        float x;
        if (cc < 1024) { int j = cc - 512, f = j >> 6, e = j & 63;
            x = item_tables[((size_t)f * V_ + target_ad[b * 8 + f]) * 64 + e]; }
        else if (cc < 1280) { int j = cc - 1024, pp = j >> 6, e = j & 63;
            x = profile_tables[((size_t)pp * V_ + profile_feature[b * 4 + pp]) * 64 + e]; }
        else x = context[b * 32 + (cc - 1280)];
        X[b * TOWER_IN_ + cc] = f2bf(x);
    }
}

// ---------------------------------------------------------------------------
// Kernel G: generic bf16 MFMA GEMM  C[m][n] = A[m][:K] . Bw[n][:K] + bias[n]
// grid = (N/64, M/16), 256 threads (4 waves; wave = 16-col subtile)
// 2 independent acc chains + unroll to batch loads / break MFMA dep chain.
// ---------------------------------------------------------------------------
__global__ __launch_bounds__(256) void gemm_kernel(
    const unsigned short* __restrict__ A, const unsigned short* __restrict__ Bw,
    const float* __restrict__ bias, float* __restrict__ C, int K, int N)
{
    const int t = threadIdx.x;
    const int wv = t >> 6, lane = t & 63, quad = lane >> 4, cl = lane & 15;
    const int n0 = blockIdx.x * 64 + wv * 16;
    const int m0 = blockIdx.y * 16;
    f4v acc0 = {0.f, 0.f, 0.f, 0.f};
    f4v acc1 = {0.f, 0.f, 0.f, 0.f};
    const unsigned short* arow = A + (size_t)(m0 + cl) * K + quad * 8;
    const unsigned short* brow = Bw + (size_t)(n0 + cl) * K + quad * 8;
    int k0 = 0;
    #pragma unroll 2
    for (; k0 + 64 <= K; k0 += 64) {
        bf8v a0 = *(const bf8v*)(arow + k0);
        bf8v b0 = *(const bf8v*)(brow + k0);
        bf8v a1 = *(const bf8v*)(arow + k0 + 32);
        bf8v b1 = *(const bf8v*)(brow + k0 + 32);
        acc0 = __builtin_amdgcn_mfma_f32_16x16x32_bf16(a0, b0, acc0, 0, 0, 0);
        acc1 = __builtin_amdgcn_mfma_f32_16x16x32_bf16(a1, b1, acc1, 0, 0, 0);
    }
    if (k0 < K) {
        bf8v a = *(const bf8v*)(arow + k0);
        bf8v b = *(const bf8v*)(brow + k0);
        acc0 = __builtin_amdgcn_mfma_f32_16x16x32_bf16(a, b, acc0, 0, 0, 0);
    }
    float bv = bias[n0 + cl];
    #pragma unroll
    for (int j = 0; j < 4; ++j)
        C[(size_t)(m0 + quad * 4 + j) * N + n0 + cl] = acc0[j] + acc1[j] + bv;
}

// ---------------------------------------------------------------------------
// Kernel N: rowwise LN + ReLU -> bf16.  grid = 256 (one row per block).
// ---------------------------------------------------------------------------
__global__ __launch_bounds__(256) void ln_relu_kernel(
    const float* __restrict__ C, const float* __restrict__ g,
    const float* __restrict__ bb, unsigned short* __restrict__ Hx, int N)
{
    __shared__ float sRed[4];
    const int b = blockIdx.x, t = threadIdx.x;
    float s = 0.f, s2 = 0.f;
    for (int j = t; j < N; j += 256) { float x = C[(size_t)b * N + j]; s += x; s2 += x * x; }
    s  = block_reduce_sum(s,  sRed);
    __syncthreads();
    s2 = block_reduce_sum(s2, sRed);
    float invN = 1.f / (float)N;
    float mean = s * invN;
    float var  = s2 * invN - mean * mean;
    float rst  = rsqrtf(fmaxf(var, 0.f) + LN_EPS);
    for (int j = t; j < N; j += 256) {
        float x = C[(size_t)b * N + j];
        Hx[(size_t)b * N + j] = f2bf(fmaxf((x - mean) * rst * g[j] + bb[j], 0.f));
    }
}

// ---------------------------------------------------------------------------
// Kernel F: final LN + ReLU + dot(w4) + sigmoid.  grid = 256.
// ---------------------------------------------------------------------------
__global__ __launch_bounds__(256) void final_kernel(
    const float* __restrict__ C3, const float* __restrict__ g3,
    const float* __restrict__ bb3, const float* __restrict__ w4,
    const float* __restrict__ b4, float* __restrict__ out)
{
    __shared__ float sRed[4];
    const int b = blockIdx.x, t = threadIdx.x;
    float x = C3[b * 256 + t];
    float s = block_reduce_sum(x, sRed);
    float mean = s * (1.f / 256.f);
    float d = x - mean;
    __syncthreads();
    float q = block_reduce_sum(d * d, sRed);
    float rst = rsqrtf(q * (1.f / 256.f) + LN_EPS);
    float h = fmaxf(d * rst * g3[t] + bb3[t], 0.f);
    __syncthreads();
    float p = block_reduce_sum(h * w4[t], sRed);
    if (t == 0) out[b] = 1.f / (1.f + expf(-(p + b4[0])));
}

// ---------------------------------------------------------------------------
extern "C" void kernel_launch(void* const* d_in, const int* in_sizes, int n_in,
                              void* d_out, int out_size, void* d_ws, size_t ws_size,
                              hipStream_t stream)
{
    (void)in_sizes; (void)n_in; (void)out_size; (void)ws_size;
    const int*   target_ad       = (const int*)d_in[0];
    const int*   ubs_feature     = (const int*)d_in[1];
    const int*   profile_feature = (const int*)d_in[2];
    const float* context         = (const float*)d_in[3];
    const float* item_tables     = (const float*)d_in[4];
    const float* profile_tables  = (const float*)d_in[5];
    const float* q_w   = (const float*)d_in[6];
    const float* k_w   = (const float*)d_in[7];
    const float* v_w   = (const float*)d_in[8];
    const float* lin_w = (const float*)d_in[9];
    const float* lin_b = (const float*)d_in[10];
    const float* ln_g  = (const float*)d_in[11];
    const float* ln_b  = (const float*)d_in[12];
    const float* t_w1  = (const float*)d_in[13];
    const float* t_b1  = (const float*)d_in[14];
    const float* t_g1  = (const float*)d_in[15];
    const float* t_bb1 = (const float*)d_in[16];
    const float* t_w2  = (const float*)d_in[17];
    const float* t_b2  = (const float*)d_in[18];
    const float* t_g2  = (const float*)d_in[19];
    const float* t_bb2 = (const float*)d_in[20];
    const float* t_w3  = (const float*)d_in[21];
    const float* t_b3  = (const float*)d_in[22];
    const float* t_g3  = (const float*)d_in[23];
    const float* t_bb3 = (const float*)d_in[24];
    const float* t_w4  = (const float*)d_in[25];
    const float* t_b4  = (const float*)d_in[26];

    char* ws = (char*)d_ws;
    unsigned short* wsMT = (unsigned short*)(ws);              //  3,276,800
    unsigned short* wsWT = (unsigned short*)(ws +  3276800);   //  3,276,800
    float* ubs_acc       = (float*)         (ws +  6553600);   //    524,288
    unsigned short* Wt1  = (unsigned short*)(ws +  7077888);   //  2,686,976
    unsigned short* Wt2  = (unsigned short*)(ws +  9764864);   //  1,048,576
    unsigned short* Wt3  = (unsigned short*)(ws + 10813440);   //    262,144
    unsigned short* X    = (unsigned short*)(ws + 11075584);   //    671,744
    float*          C1   = (float*)         (ws + 11747328);   //  1,048,576
    unsigned short* H1   = (unsigned short*)(ws + 12795904);   //    524,288
    float*          C2   = (float*)         (ws + 13320192);   //    524,288
    unsigned short* H2   = (unsigned short*)(ws + 13844480);   //    262,144
    float*          C3   = (float*)         (ws + 14106624);   //    262,144 (end 14,368,768)

    hipMemsetAsync(ubs_acc, 0, B_ * F_ * E_ * sizeof(float), stream);

    prep_kernel<<<1952, 256, 0, stream>>>(t_w1, t_w2, t_w3, Wt1, Wt2, Wt3);
    precomp_kernel<<<L_ * H_, 256, 0, stream>>>(q_w, k_w, v_w, lin_w, wsMT, wsWT);
    attn_kernel<<<NCH_ * 32, 256, 0, stream>>>(ubs_feature, item_tables, wsMT, wsWT,
                                               lin_b, ln_g, ln_b, ubs_acc);
    reduceX_kernel<<<B_, 256, 0, stream>>>(ubs_acc, target_ad, profile_feature, context,
                                           item_tables, profile_tables, X);
    gemm_kernel<<<dim3(16, 16), 256, 0, stream>>>(X,  Wt1, t_b1, C1, 1312, 1024);
    ln_relu_kernel<<<B_, 256, 0, stream>>>(C1, t_g1, t_bb1, H1, 1024);
    gemm_kernel<<<dim3(8, 16),  256, 0, stream>>>(H1, Wt2, t_b2, C2, 1024, 512);
    ln_relu_kernel<<<B_, 256, 0, stream>>>(C2, t_g2, t_bb2, H2, 512);
    gemm_kernel<<<dim3(4, 16),  256, 0, stream>>>(H2, Wt3, t_b3, C3, 512, 256);
    final_kernel<<<B_, 256, 0, stream>>>(C3, t_g3, t_bb3, t_w4, t_b4, (float*)d_out);
}